// Round 1
// baseline (2157.769 us; speedup 1.0000x reference)
//
#include <hip/hip_runtime.h>
#include <cstdint>
#include <cstddef>

#define SS 200
#define NV 100001   // V+1

using short8 = __attribute__((ext_vector_type(8))) short;
using f32x4  = __attribute__((ext_vector_type(4))) float;

__device__ __forceinline__ unsigned short f2bf(float f){
  unsigned int x = __float_as_uint(f);
  x += 0x7fffu + ((x >> 16) & 1u);
  return (unsigned short)(x >> 16);
}
__device__ __forceinline__ float sigm(float x){
  return __builtin_amdgcn_rcpf(1.0f + exp2f(x * -1.44269504f));
}

#define MFB(a,b,c) __builtin_amdgcn_mfma_f32_16x16x32_bf16((a),(b),(c),0,0,0)
#define MF8(a,b,c) __builtin_amdgcn_mfma_f32_16x16x32_fp8_fp8((a),(b),(c),0,0,0)

// ---------------- prep: swizzle weights into MFMA-fragment order, transpose tokens ----
// rb  : rec_kernel bf16 frags  [w(8)][t(8)][kt(8)][lane(64)][j(8)]  (262144 elems)
// kb8 : kernel fp8 frags       [w(8)][t(8)][kt(2)][lane(64)][j(8)]  (65536 bytes)
// tokT: tokens transposed [s][b]
__global__ void prep_kernel(const int* __restrict__ inp,
                            const float* __restrict__ kern,
                            const float* __restrict__ rec,
                            unsigned short* __restrict__ rb,
                            unsigned char* __restrict__ kb8,
                            int* __restrict__ tokT){
  int idx = blockIdx.x * 256 + threadIdx.x;
  if (idx < 262144){
    int j = idx & 7, lane = (idx >> 3) & 63, fid = idx >> 9;
    int kt = fid & 7, t = (fid >> 3) & 7, w = fid >> 6;
    int gg = t >> 1, hh = t & 1;
    int k   = kt * 32 + (lane >> 4) * 8 + j;
    int col = gg * 256 + w * 32 + hh * 16 + (lane & 15);
    rb[idx] = f2bf(rec[k * 1024 + col]);
  }
  if (idx < 65536){
    int j = idx & 7, lane = (idx >> 3) & 63, fid = idx >> 9;  // fid < 128
    int kt = fid & 1, t = (fid >> 1) & 7, w = fid >> 4;
    int gg = t >> 1, hh = t & 1;
    int k   = kt * 32 + (lane >> 4) * 8 + j;
    int col = gg * 256 + w * 32 + hh * 16 + (lane & 15);
    int p = __builtin_amdgcn_cvt_pk_fp8_f32(kern[k * 1024 + col], 0.0f, 0, false);
    kb8[idx] = (unsigned char)(p & 0xff);
  }
  if (idx < 204800){
    int s = idx >> 10, b = idx & 1023;
    tokT[idx] = inp[b * SS + s];
  }
}

// ---------------- LSTM: 64 blocks x 512 thr (8 waves), 16 batch rows per block ------
// wave w owns u in [32w,32w+32) for ALL four gates: C-tiles t=gg*2+hh at col 256gg+32w+16hh
// LDS: h_lds(8K, A-frag order) | xA(1K fp8 A-frags) | rBl(64K rec kt4) | kBl(64K kernel fp8)
__global__ void __launch_bounds__(512, 2)
lstm_kernel(const float* __restrict__ emb,
            const float* __restrict__ bias,
            const unsigned short* __restrict__ rb,
            const unsigned char* __restrict__ kb8,
            const int* __restrict__ tokT,
            float* __restrict__ hout){
  extern __shared__ char smem[];
  char* const h_lds = smem;               // 8192
  char* const xA    = smem + 8192;        // 1024
  char* const rBl   = smem + 9216;        // 65536
  char* const kBl   = smem + 74752;       // 65536
  const int tid  = threadIdx.x;
  const int lane = tid & 63;
  const int w    = tid >> 6;
  const int l15  = lane & 15;
  const int l4   = lane >> 4;
  const int b0   = blockIdx.x << 4;

  #define RBFRAG(t,kt) (*(const short8*)(rb + ((w*8+(t))*8+(kt))*512 + (lane<<3)))

  // resident rec frags kt0-3
  short8 Wr[8][4];
  #pragma unroll
  for (int t = 0; t < 8; ++t)
    #pragma unroll
    for (int kt = 0; kt < 4; ++kt)
      Wr[t][kt] = RBFRAG(t, kt);
  // rec kt4 -> LDS
  #pragma unroll
  for (int t = 0; t < 8; ++t){
    short8 v = RBFRAG(t, 4);
    *(short8*)(rBl + w*8192 + t*1024 + (lane<<4)) = v;
  }
  // kernel fp8 frags -> LDS
  #pragma unroll
  for (int f = 0; f < 16; ++f){
    long v = *(const long*)(kb8 + (w*16+f)*512 + (lane<<3));
    *(long*)(kBl + w*8192 + f*512 + (lane<<3)) = v;
  }
  float biasv[8];
  #pragma unroll
  for (int t = 0; t < 8; ++t){
    int gg = t >> 1, hh = t & 1;
    biasv[t] = bias[gg*256 + w*32 + hh*16 + l15];
  }
  *(f32x4*)(h_lds + tid*16) = f32x4{0.f,0.f,0.f,0.f};

  float c[2][4], hr[2][4];
  #pragma unroll
  for (int hh = 0; hh < 2; ++hh)
    #pragma unroll
    for (int r = 0; r < 4; ++r){ c[hh][r] = 0.f; hr[hh][r] = 0.f; }

  // x-staging role: thread -> (row, 2 emb elems)
  const int row = tid >> 5;        // 0..15
  const int e0  = (tid & 31) * 2;  // 0..62
  {
    int tok0 = tokT[b0 + row];
    float2 xv = *(const float2*)(emb + (size_t)tok0 * 64 + e0);
    int p = __builtin_amdgcn_cvt_pk_fp8_f32(xv.x, xv.y, 0, false);
    int kt = e0 >> 5, lp = row + (((e0 & 31) >> 3) << 4), j = e0 & 7;
    *(unsigned short*)(xA + kt*512 + lp*8 + j) = (unsigned short)(p & 0xffff);
  }
  __syncthreads();

  #pragma unroll 1
  for (int s = 0; s < SS; ++s){
    int tok_n = 0;
    if (s + 1 < SS) tok_n = tokT[(s+1)*1024 + b0 + row];
    int4 mtok = *(const int4*)(tokT + s*1024 + b0 + (l4 << 2));

    f32x4 acc[8];
    #pragma unroll
    for (int t = 0; t < 8; ++t) acc[t] = f32x4{biasv[t],biasv[t],biasv[t],biasv[t]};

    // stream kt5 early
    short8 Wsa[4], Wsb[4];
    #pragma unroll
    for (int q = 0; q < 4; ++q) Wsa[q] = RBFRAG(q, 5);
    #pragma unroll
    for (int q = 0; q < 4; ++q) Wsb[q] = RBFRAG(4+q, 5);

    // rec kt0-3 (VGPR-resident B)
    #pragma unroll
    for (int kt = 0; kt < 4; ++kt){
      short8 a = *(const short8*)(h_lds + kt*1024 + (lane<<4));
      #pragma unroll
      for (int t = 0; t < 8; ++t) acc[t] = MFB(a, Wr[t][kt], acc[t]);
    }
    // rec kt4 (LDS B)
    {
      short8 a = *(const short8*)(h_lds + 4*1024 + (lane<<4));
      #pragma unroll
      for (int t = 0; t < 8; ++t){
        short8 bf = *(const short8*)(rBl + w*8192 + t*1024 + (lane<<4));
        acc[t] = MFB(a, bf, acc[t]);
      }
    }
    // rec kt5 (streamed), reissue kt6
    {
      short8 a = *(const short8*)(h_lds + 5*1024 + (lane<<4));
      #pragma unroll
      for (int q = 0; q < 4; ++q) acc[q]   = MFB(a, Wsa[q], acc[q]);
      #pragma unroll
      for (int q = 0; q < 4; ++q) Wsa[q] = RBFRAG(q, 6);
      #pragma unroll
      for (int q = 0; q < 4; ++q) acc[4+q] = MFB(a, Wsb[q], acc[4+q]);
      #pragma unroll
      for (int q = 0; q < 4; ++q) Wsb[q] = RBFRAG(4+q, 6);
    }
    // rec kt6, reissue kt7
    {
      short8 a = *(const short8*)(h_lds + 6*1024 + (lane<<4));
      #pragma unroll
      for (int q = 0; q < 4; ++q) acc[q]   = MFB(a, Wsa[q], acc[q]);
      #pragma unroll
      for (int q = 0; q < 4; ++q) Wsa[q] = RBFRAG(q, 7);
      #pragma unroll
      for (int q = 0; q < 4; ++q) acc[4+q] = MFB(a, Wsb[q], acc[4+q]);
      #pragma unroll
      for (int q = 0; q < 4; ++q) Wsb[q] = RBFRAG(4+q, 7);
    }
    // rec kt7
    {
      short8 a = *(const short8*)(h_lds + 7*1024 + (lane<<4));
      #pragma unroll
      for (int q = 0; q < 4; ++q) acc[q]   = MFB(a, Wsa[q], acc[q]);
      #pragma unroll
      for (int q = 0; q < 4; ++q) acc[4+q] = MFB(a, Wsb[q], acc[4+q]);
    }
    // x-part (fp8)
    #pragma unroll
    for (int kt = 0; kt < 2; ++kt){
      long ax = *(const long*)(xA + kt*512 + (lane<<3));
      #pragma unroll
      for (int t = 0; t < 8; ++t){
        long bx = *(const long*)(kBl + w*8192 + (t*2+kt)*512 + (lane<<3));
        acc[t] = MF8(ax, bx, acc[t]);
      }
    }

    // prefetch next x tile (latency hidden under gate VALU)
    float2 xvn = make_float2(0.f, 0.f);
    if (s + 1 < SS) xvn = *(const float2*)(emb + (size_t)tok_n * 64 + e0);

    // gates: all-sigmoid LSTM variant; masked rows keep state
    #pragma unroll
    for (int hh = 0; hh < 2; ++hh){
      #pragma unroll
      for (int r = 0; r < 4; ++r){
        float zi = acc[0+hh][r];
        float zf = acc[2+hh][r];
        float zg = acc[4+hh][r];
        float zo = acc[6+hh][r];
        float si = sigm(zi), sf = sigm(zf), sg = sigm(zg), so = sigm(zo);
        float cn = sf * c[hh][r] + si * sg;
        float hn = so * sigm(cn);
        int tk = (r==0) ? mtok.x : (r==1) ? mtok.y : (r==2) ? mtok.z : mtok.w;
        if (tk != 0){ c[hh][r] = cn; hr[hh][r] = hn; }
      }
    }
    __syncthreads();
    // write h (bf16) into A-frag order: wave w owns kt=w region
    #pragma unroll
    for (int hh = 0; hh < 2; ++hh){
      #pragma unroll
      for (int r = 0; r < 4; ++r){
        int u31 = hh*16 + l15;
        int lp = ((l4<<2) + r) + ((u31 >> 3) << 4);
        *(unsigned short*)(h_lds + w*1024 + lp*16 + ((lane & 7) << 1)) = f2bf(hr[hh][r]);
      }
    }
    if (s + 1 < SS){
      int p = __builtin_amdgcn_cvt_pk_fp8_f32(xvn.x, xvn.y, 0, false);
      int kt = e0 >> 5, lp = row + (((e0 & 31) >> 3) << 4), j = e0 & 7;
      *(unsigned short*)(xA + kt*512 + lp*8 + j) = (unsigned short)(p & 0xffff);
    }
    __syncthreads();
  }

  // final h (fp32)
  #pragma unroll
  for (int hh = 0; hh < 2; ++hh)
    #pragma unroll
    for (int r = 0; r < 4; ++r){
      int b = b0 + (l4<<2) + r;
      int u = w*32 + hh*16 + l15;
      hout[b*256 + u] = hr[hh][r];
    }
  #undef RBFRAG
}

// ---------------- dense: out = h @ dense_w + dense_b  (1024x64, K=256) --------------
__global__ void dense_kernel(const float* __restrict__ h,
                             const float* __restrict__ dw,
                             const float* __restrict__ db,
                             float* __restrict__ outv){
  int tid = threadIdx.x;
  int e = tid & 63;
  int b = blockIdx.x * 4 + (tid >> 6);
  const float* hb = h + b * 256;
  float a = db[e];
  #pragma unroll 8
  for (int u = 0; u < 256; ++u) a = fmaf(hb[u], dw[u*64 + e], a);
  outv[b*64 + e] = a;
}

// ---------------- logits: dst = out @ emb.T  (1024 x 100001, K=64, fp32) ------------
__global__ void __launch_bounds__(256)
logits_kernel(const float* __restrict__ outv,
              const float* __restrict__ emb,
              float* __restrict__ dst){
  int v = blockIdx.x * 256 + threadIdx.x;
  const bool valid = (v < NV);
  const int vs = valid ? v : 0;
  float er[64];
  #pragma unroll
  for (int q = 0; q < 16; ++q){
    float4 tq = *(const float4*)(emb + (size_t)vs * 64 + q*4);
    er[q*4+0] = tq.x; er[q*4+1] = tq.y; er[q*4+2] = tq.z; er[q*4+3] = tq.w;
  }
  for (int b = 0; b < 1024; ++b){
    const float* ob = outv + b*64;   // wave-uniform -> scalar loads
    float a0 = 0.f, a1 = 0.f;
    #pragma unroll
    for (int e = 0; e < 64; e += 2){
      a0 = fmaf(ob[e],   er[e],   a0);
      a1 = fmaf(ob[e+1], er[e+1], a1);
    }
    if (valid) dst[(size_t)b * NV + v] = a0 + a1;
  }
}

extern "C" void kernel_launch(void* const* d_in, const int* in_sizes, int n_in,
                              void* d_out, int out_size, void* d_ws, size_t ws_size,
                              hipStream_t stream){
  const int*   inp  = (const int*)  d_in[0];
  const float* emb  = (const float*)d_in[1];
  const float* kern = (const float*)d_in[2];
  const float* rec  = (const float*)d_in[3];
  const float* bias = (const float*)d_in[4];
  const float* dw   = (const float*)d_in[5];
  const float* db   = (const float*)d_in[6];
  float* dst = (float*)d_out;
  char* ws = (char*)d_ws;

  unsigned short* rb   = (unsigned short*)(ws);            // 524288 B
  unsigned char*  kb8  = (unsigned char*) (ws + 524288);   // 65536 B
  int*            tokT = (int*)           (ws + 589824);   // 819200 B
  float*          hbuf = (float*)         (ws + 1409024);  // 1048576 B
  float*          obuf = (float*)         (ws + 2457600);  // 262144 B

  const int SMEM_BYTES = 140288;
  hipFuncSetAttribute((const void*)lstm_kernel,
                      hipFuncAttributeMaxDynamicSharedMemorySize, SMEM_BYTES);

  prep_kernel  <<<1024, 256, 0, stream>>>(inp, kern, rec, rb, kb8, tokT);
  lstm_kernel  <<<64, 512, SMEM_BYTES, stream>>>(emb, bias, rb, kb8, tokT, hbuf);
  dense_kernel <<<256, 256, 0, stream>>>(hbuf, dw, db, obuf);
  logits_kernel<<<391, 256, 0, stream>>>(obuf, emb, dst);
  (void)in_sizes; (void)n_in; (void)out_size; (void)ws_size;
}

// Round 2
// 1859.589 us; speedup vs baseline: 1.1603x; 1.1603x over previous
//
#include <hip/hip_runtime.h>
#include <cstdint>
#include <cstddef>

#define SS 200
#define NV 100001   // V+1

using short8 = __attribute__((ext_vector_type(8))) short;
using f32x4  = __attribute__((ext_vector_type(4))) float;

__device__ __forceinline__ unsigned short f2bf(float f){
  unsigned int x = __float_as_uint(f);
  x += 0x7fffu + ((x >> 16) & 1u);
  return (unsigned short)(x >> 16);
}
__device__ __forceinline__ float sigm(float x){
  return __builtin_amdgcn_rcpf(1.0f + exp2f(x * -1.44269504f));
}

#define MFB(a,b,c) __builtin_amdgcn_mfma_f32_16x16x32_bf16((a),(b),(c),0,0,0)
#define MF8(a,b,c) __builtin_amdgcn_mfma_f32_16x16x32_fp8_fp8((a),(b),(c),0,0,0)

// ---------------- prep: coalesced-read weight swizzle + token transpose -------------
// rb  : rec_kernel bf16 frags  [w(8)][t(8)][kt(8)][lane(64)][j(8)]
// kb8 : kernel fp8 frags       [w(8)][t(8)][kt(2)][lane(64)][j(8)]
// tokT: tokens transposed [s][b]
__global__ void prep_kernel(const int* __restrict__ inp,
                            const float* __restrict__ kern,
                            const float* __restrict__ rec,
                            unsigned short* __restrict__ rb,
                            unsigned char* __restrict__ kb8,
                            int* __restrict__ tokT){
  int idx = blockIdx.x * 256 + threadIdx.x;
  if (idx < 262144){                    // rec: 256 x 1024, coalesced read
    int k = idx >> 10, col = idx & 1023;
    int gg = col >> 8, w = (col >> 5) & 7, hh = (col >> 4) & 1, l15 = col & 15;
    int kt = k >> 5, hi = (k >> 3) & 3, j = k & 7;
    int lane = l15 + (hi << 4);
    int t = gg * 2 + hh;
    rb[(((w*8 + t)*8 + kt) << 9) + lane*8 + j] = f2bf(rec[idx]);
  }
  if (idx < 65536){                     // kernel: 64 x 1024
    int k = idx >> 10, col = idx & 1023;
    int gg = col >> 8, w = (col >> 5) & 7, hh = (col >> 4) & 1, l15 = col & 15;
    int kt = k >> 5, hi = (k >> 3) & 3, j = k & 7;
    int lane = l15 + (hi << 4);
    int t = gg * 2 + hh;
    int p = __builtin_amdgcn_cvt_pk_fp8_f32(kern[idx], 0.0f, 0, false);
    kb8[(((w*8 + t)*2 + kt) << 9) + lane*8 + j] = (unsigned char)(p & 0xff);
  }
  if (idx < 204800){                    // token transpose
    int s = idx >> 10, b = idx & 1023;
    tokT[idx] = inp[b * SS + s];
  }
}

// ---------------- LSTM: 64 blocks x 512 thr (8 waves), 16 batch rows per block ------
// Swapped MFMA: A = weights (M = z), B = h/x (N = batch). D: row=z(l4*4+r), col=batch(l15).
// LDS: h[2](16K) | xA[2](2K) | rBl kt4 (64K) | kBl fp8 (64K) | biasL (4K) = 150K
__global__ void __launch_bounds__(512, 1)
lstm_kernel(const float* __restrict__ emb,
            const float* __restrict__ bias,
            const unsigned short* __restrict__ rb,
            const unsigned char* __restrict__ kb8,
            const int* __restrict__ tokT,
            float* __restrict__ hout){
  extern __shared__ char smem[];
  char*  const hbuf0 = smem;                    // 2 x 8192
  char*  const xbuf0 = smem + 16384;            // 2 x 1024
  char*  const rBl   = smem + 18432;            // 65536 (rec kt4)
  char*  const kBl   = smem + 83968;            // 65536 (kernel fp8)
  float* const biasL = (float*)(smem + 149504); // 4096
  const int tid  = threadIdx.x;
  const int lane = tid & 63;
  const int w    = tid >> 6;
  const int l15  = lane & 15;
  const int l4   = lane >> 4;
  const int b0   = blockIdx.x << 4;

  #define RBF(t,kt) (*(const short8*)(rb + (((w*8+(t))*8+(kt)) << 9) + (lane<<3)))

  // resident rec frags kt0-3 (128 VGPR)
  short8 Wr[4][8];
  #pragma unroll
  for (int kt = 0; kt < 4; ++kt)
    #pragma unroll
    for (int t = 0; t < 8; ++t) Wr[kt][t] = RBF(t, kt);
  // rec kt4 -> LDS
  #pragma unroll
  for (int t = 0; t < 8; ++t){
    short8 v = RBF(t, 4);
    *(short8*)(rBl + w*8192 + t*1024 + (lane<<4)) = v;
  }
  // kernel fp8 frags -> LDS
  #pragma unroll
  for (int f = 0; f < 16; ++f){
    long v = *(const long*)(kb8 + (w*16 + f)*512 + (lane<<3));
    *(long*)(kBl + w*8192 + f*512 + (lane<<3)) = v;
  }
  for (int i = tid; i < 1024; i += 512) biasL[i] = bias[i];
  *(f32x4*)(hbuf0 + tid*16) = f32x4{0.f,0.f,0.f,0.f};

  // stream buffer: kt5 for step 0
  short8 S[8];
  #pragma unroll
  for (int t = 0; t < 8; ++t) S[t] = RBF(t, 5);

  float c[2][4], hr[2][4];
  #pragma unroll
  for (int hh = 0; hh < 2; ++hh)
    #pragma unroll
    for (int r = 0; r < 4; ++r){ c[hh][r] = 0.f; hr[hh][r] = 0.f; }

  const int row = tid >> 5;        // x-staging role: batch row 0..15
  const int e0  = (tid & 31) << 1; // emb elems e0, e0+1
  __syncthreads();
  {
    int tok0 = tokT[b0 + row];
    float2 xv = *(const float2*)(emb + (size_t)tok0 * 64 + e0);
    int p = __builtin_amdgcn_cvt_pk_fp8_f32(xv.x, xv.y, 0, false);
    int kt = e0 >> 5, lp = row + (((e0 & 31) >> 3) << 4), j = e0 & 7;
    *(unsigned short*)(xbuf0 + kt*512 + lp*8 + j) = (unsigned short)(p & 0xffff);
  }
  __syncthreads();

  #pragma unroll 1
  for (int s = 0; s < SS; ++s){
    char* const hc = hbuf0 + ((s & 1) << 13);
    char* const hn = hbuf0 + (((s & 1) ^ 1) << 13);
    char* const xc = xbuf0 + ((s & 1) << 10);
    char* const xn = xbuf0 + (((s & 1) ^ 1) << 10);

    // mask token (this step) + x prefetch (next step) — issued early
    int tk = tokT[s*1024 + b0 + l15];
    float2 xv = make_float2(0.f, 0.f);
    if (s + 1 < SS){
      int tok_n = tokT[(s+1)*1024 + b0 + row];
      xv = *(const float2*)(emb + (size_t)tok_n * 64 + e0);
    }

    // acc init from bias (broadcast ds_read_b128)
    f32x4 acc[8];
    #pragma unroll
    for (int t = 0; t < 8; ++t){
      int gg = t >> 1, hh = t & 1;
      acc[t] = *(const f32x4*)(biasL + gg*256 + w*32 + hh*16 + (l4<<2));
    }

    // kt5 (S ready from previous step / prologue)
    {
      short8 h5 = *(const short8*)(hc + 5*1024 + (lane<<4));
      #pragma unroll
      for (int t = 0; t < 8; ++t) acc[t] = MFB(S[t], h5, acc[t]);
    }
    #pragma unroll
    for (int t = 0; t < 8; ++t) S[t] = RBF(t, 6);   // issue kt6

    // kt0-3 (VGPR-resident weights) — covers kt6 latency
    #pragma unroll
    for (int kt = 0; kt < 4; ++kt){
      short8 h = *(const short8*)(hc + kt*1024 + (lane<<4));
      #pragma unroll
      for (int t = 0; t < 8; ++t) acc[t] = MFB(Wr[kt][t], h, acc[t]);
    }

    // kt6
    {
      short8 h6 = *(const short8*)(hc + 6*1024 + (lane<<4));
      #pragma unroll
      for (int t = 0; t < 8; ++t) acc[t] = MFB(S[t], h6, acc[t]);
    }
    #pragma unroll
    for (int t = 0; t < 8; ++t) S[t] = RBF(t, 7);   // issue kt7

    // kt4 (LDS) + x0 (fp8) — covers kt7 latency
    {
      short8 h4 = *(const short8*)(hc + 4*1024 + (lane<<4));
      #pragma unroll
      for (int t = 0; t < 8; ++t){
        short8 bw = *(const short8*)(rBl + w*8192 + t*1024 + (lane<<4));
        acc[t] = MFB(bw, h4, acc[t]);
      }
    }
    {
      long ax = *(const long*)(xc + (lane<<3));
      #pragma unroll
      for (int t = 0; t < 8; ++t){
        long bx = *(const long*)(kBl + w*8192 + (t*2)*512 + (lane<<3));
        acc[t] = MF8(bx, ax, acc[t]);
      }
    }

    // kt7
    {
      short8 h7 = *(const short8*)(hc + 7*1024 + (lane<<4));
      #pragma unroll
      for (int t = 0; t < 8; ++t) acc[t] = MFB(S[t], h7, acc[t]);
    }
    #pragma unroll
    for (int t = 0; t < 8; ++t) S[t] = RBF(t, 5);   // issue kt5 for NEXT step

    // x1 (fp8)
    {
      long ax = *(const long*)(xc + 512 + (lane<<3));
      #pragma unroll
      for (int t = 0; t < 8; ++t){
        long bx = *(const long*)(kBl + w*8192 + (t*2+1)*512 + (lane<<3));
        acc[t] = MF8(bx, ax, acc[t]);
      }
    }

    // gates: all-sigmoid LSTM; masked rows keep state; h write packs 4 bf16 -> b64
    #pragma unroll
    for (int hh = 0; hh < 2; ++hh){
      unsigned long long pk = 0ull;
      #pragma unroll
      for (int r = 0; r < 4; ++r){
        float zi = acc[0+hh][r];
        float zf = acc[2+hh][r];
        float zg = acc[4+hh][r];
        float zo = acc[6+hh][r];
        float si = sigm(zi), sf = sigm(zf), sg = sigm(zg), so = sigm(zo);
        float cn = sf * c[hh][r] + si * sg;
        float hv = so * sigm(cn);
        if (tk != 0){ c[hh][r] = cn; hr[hh][r] = hv; }
        pk |= ((unsigned long long)f2bf(hr[hh][r])) << (16*r);
      }
      int lane_a = l15 + ((hh*2 + (l4 >> 1)) << 4);
      *(unsigned long long*)(hn + (w<<10) + lane_a*16 + ((l4 & 1) << 3)) = pk;
    }

    // stage next x (fp8)
    if (s + 1 < SS){
      int p = __builtin_amdgcn_cvt_pk_fp8_f32(xv.x, xv.y, 0, false);
      int kt = e0 >> 5, lp = row + (((e0 & 31) >> 3) << 4), j = e0 & 7;
      *(unsigned short*)(xn + kt*512 + lp*8 + j) = (unsigned short)(p & 0xffff);
    }
    __syncthreads();   // single barrier per step (double-buffered h & x)
  }

  // final h (fp32)
  #pragma unroll
  for (int hh = 0; hh < 2; ++hh){
    *(float4*)(hout + (b0 + l15)*256 + w*32 + hh*16 + (l4<<2)) =
        make_float4(hr[hh][0], hr[hh][1], hr[hh][2], hr[hh][3]);
  }
  #undef RBF
}

// ---------------- dense: out = h @ dense_w + dense_b  (1024x64, K=256) --------------
__global__ void dense_kernel(const float* __restrict__ h,
                             const float* __restrict__ dw,
                             const float* __restrict__ db,
                             float* __restrict__ outv){
  int tid = threadIdx.x;
  int e = tid & 63;
  int b = blockIdx.x * 4 + (tid >> 6);
  const float* hb = h + b * 256;
  float a = db[e];
  #pragma unroll 8
  for (int u = 0; u < 256; ++u) a = fmaf(hb[u], dw[u*64 + e], a);
  outv[b*64 + e] = a;
}

// ---------------- logits: dst = out @ emb.T  (1024 x 100001, K=64, fp32) ------------
// batch split over gridDim.y for occupancy (1564 blocks)
__global__ void __launch_bounds__(256)
logits_kernel(const float* __restrict__ outv,
              const float* __restrict__ emb,
              float* __restrict__ dst){
  int v = blockIdx.x * 256 + threadIdx.x;
  const bool valid = (v < NV);
  const int vs = valid ? v : 0;
  const int bb = blockIdx.y * 256;
  float er[64];
  #pragma unroll
  for (int q = 0; q < 16; ++q){
    float4 tq = *(const float4*)(emb + (size_t)vs * 64 + q*4);
    er[q*4+0] = tq.x; er[q*4+1] = tq.y; er[q*4+2] = tq.z; er[q*4+3] = tq.w;
  }
  for (int b = bb; b < bb + 256; ++b){
    const float* ob = outv + b*64;   // wave-uniform -> scalar loads
    float a0 = 0.f, a1 = 0.f;
    #pragma unroll
    for (int e = 0; e < 64; e += 2){
      a0 = fmaf(ob[e],   er[e],   a0);
      a1 = fmaf(ob[e+1], er[e+1], a1);
    }
    if (valid) dst[(size_t)b * NV + v] = a0 + a1;
  }
}

extern "C" void kernel_launch(void* const* d_in, const int* in_sizes, int n_in,
                              void* d_out, int out_size, void* d_ws, size_t ws_size,
                              hipStream_t stream){
  const int*   inp  = (const int*)  d_in[0];
  const float* emb  = (const float*)d_in[1];
  const float* kern = (const float*)d_in[2];
  const float* rec  = (const float*)d_in[3];
  const float* bias = (const float*)d_in[4];
  const float* dw   = (const float*)d_in[5];
  const float* db   = (const float*)d_in[6];
  float* dst = (float*)d_out;
  char* ws = (char*)d_ws;

  unsigned short* rb   = (unsigned short*)(ws);            // 524288 B
  unsigned char*  kb8  = (unsigned char*) (ws + 524288);   // 65536 B
  int*            tokT = (int*)           (ws + 589824);   // 819200 B
  float*          hbuf = (float*)         (ws + 1409024);  // 1048576 B
  float*          obuf = (float*)         (ws + 2457600);  // 262144 B

  const int SMEM_BYTES = 153600;
  hipFuncSetAttribute((const void*)lstm_kernel,
                      hipFuncAttributeMaxDynamicSharedMemorySize, SMEM_BYTES);

  prep_kernel  <<<1024, 256, 0, stream>>>(inp, kern, rec, rb, kb8, tokT);
  lstm_kernel  <<<64, 512, SMEM_BYTES, stream>>>(emb, bias, rb, kb8, tokT, hbuf);
  dense_kernel <<<256, 256, 0, stream>>>(hbuf, dw, db, obuf);
  logits_kernel<<<dim3(391, 4), 256, 0, stream>>>(obuf, emb, dst);
  (void)in_sizes; (void)n_in; (void)out_size; (void)ws_size;
}